// Round 7
// baseline (341.884 us; speedup 1.0000x reference)
//
#include <hip/hip_runtime.h>
#include <hip/hip_fp16.h>

// MSAAttention: x = e + PE; q,k,v = Linear(x); out = softmax(q k^T) v
// B=8 S=2048 H=512, fp32 in/out.
//
// Round 13: flash-style fused attention (S=qk^T + online softmax + PV in one
// kernel). Key arithmetic from R6 post-mortem: 16x16 MFMA needs an MI x NI
// register outer-product >= 4x4 to stay under the LDS/L2 bandwidth roof
// (0.25 KB/MFMA); the separate S/softmax/PV pipeline also pays 320 MB of
// HBM round-trips that fusion deletes. Per block: 64 Q-rows x 2048 keys,
// 8 waves. QK phase: wave w owns keys [512t+64w, +64), full 4x4 outer
// product, K-frags direct from XCD-pinned L2. Online softmax: R4-proven
// shfl + LDS cross-wave combine; O rescale in-register. P~ via 64KB
// swizzled LDS. PV phase: wave w owns cols [64w, +64), V-frags direct from
// L2 (vt is the exact B-operand layout). 4 steps x 4 barriers total.
// QKV stays on the R0-proven gemm6<128> 2-phase.

using half8   = __attribute__((ext_vector_type(8))) _Float16;
using half4v  = __attribute__((ext_vector_type(4))) _Float16;
using floatx4 = __attribute__((ext_vector_type(4))) float;

#define BK 32  // halves per K chunk -> 64 B LDS rows (gemm6)

#define VMCNT(N) asm volatile("s_waitcnt vmcnt(" #N ")" ::: "memory")

__device__ __forceinline__ void g2l16(const void* g, void* l) {
  // async global->LDS DMA, 16 B/lane; LDS dest = wave-uniform base + lane*16
  __builtin_amdgcn_global_load_lds((const __attribute__((address_space(1))) void*)g,
                                   (__attribute__((address_space(3))) void*)l, 16, 0, 0);
}

// ---- prep (blocks 0..8191): x16 = f16(embeds + PE)
// ---- cvt  (blocks 8192..11263): wcat f16 [1536][512] + bcat fp32 [1536]
__global__ __launch_bounds__(256) void prep_cvt_kernel(const float* __restrict__ e,
                                                       _Float16* __restrict__ x16,
                                                       const float* __restrict__ wq,
                                                       const float* __restrict__ wk,
                                                       const float* __restrict__ wv,
                                                       const float* __restrict__ bq,
                                                       const float* __restrict__ bk,
                                                       const float* __restrict__ bv,
                                                       _Float16* __restrict__ wcat,
                                                       float* __restrict__ bcat) {
  if (blockIdx.x < 8192) {
    int t = blockIdx.x * 256 + threadIdx.x;  // 2M threads, 4 elems each
    int idx = t * 4;
    int h = idx & 511;
    int s = (idx >> 9) & 2047;
    float4 ev = *(const float4*)(e + idx);
    const float ks = -9.210340371976184f / 256.0f;  // -ln(10000)/256
    float r[4] = {ev.x, ev.y, ev.z, ev.w};
#pragma unroll
    for (int j = 0; j < 4; j++) {
      int hh = h + j;
      int i = (hh < 256) ? hh : (hh - 256);
      float ang = (float)s * __expf((float)i * ks);
      r[j] += (hh < 256) ? __sinf(ang) : __cosf(ang);
    }
    half4v o = {(_Float16)r[0], (_Float16)r[1], (_Float16)r[2], (_Float16)r[3]};
    *(half4v*)(x16 + idx) = o;
  } else {
    int i = (blockIdx.x - 8192) * 256 + threadIdx.x;  // 786432
    int m = i & 262143;
    const float* s = (i < 262144) ? wq : (i < 524288) ? wk : wv;
    wcat[i] = (_Float16)s[m];
    if (i < 512) bcat[i] = bq[i];
    else if (i < 1024) bcat[i] = bk[i - 512];
    else if (i < 1536) bcat[i] = bv[i - 1024];
  }
}

// ---- gemm6 (R0-proven 2-phase): C[m][n] = sum_k A[m][k]*B[n][k] ----
// A [M,K] lda, B [N,K] ldb, k-contiguous. Tile BM x 128, BK=32, 4 waves (2x2),
// wave tile (BM/2) x 64 via 16x16x32 frags. Double-buffered LDS, one barrier
// per K-step, next tile's DMA issued right after the barrier.
// MODE 0: plain 3D grid, plain store.
// MODE 1: QKV — 1D grid 8*(2048/BM)*12, XCD decode, bias + q/k plain, v^T.
template <int BM, typename OutT, int MODE, int LBX>
__global__ __launch_bounds__(256) void gemm6(const _Float16* __restrict__ A,
                                             const _Float16* __restrict__ B,
                                             const float* __restrict__ bias,
                                             OutT* __restrict__ C,
                                             int lda, int ldb, int ldo, int K,
                                             long long sA, long long sB, long long sC,
                                             _Float16* __restrict__ oq,
                                             _Float16* __restrict__ ok,
                                             _Float16* __restrict__ ov) {
  __shared__ _Float16 Ash[2][BM * BK];
  __shared__ _Float16 Bsh[2][128 * BK];
  int bx, by, bz;
  if constexpr (MODE == 1) {
    constexpr int BYX = 2048 / BM;     // by-tiles per XCD (16384 rows / 8)
    unsigned i = blockIdx.x;
    unsigned c = i & 7, j = i >> 3;
    by = c * BYX + j / 12;
    bx = j % 12;
    bz = 0;
  } else if constexpr (MODE == 2) {
    unsigned i = blockIdx.x;
    unsigned c = i & 7, j = i >> 3;
    bz = c;
    bx = j & ((1u << LBX) - 1);
    by = j >> LBX;
  } else {
    bx = blockIdx.x; by = blockIdx.y; bz = blockIdx.z;
  }
  A += (long long)bz * sA;
  B += (long long)bz * sB;
  C += (long long)bz * sC;
  const int m0 = by * BM, n0 = bx * 128;
  const int tid = threadIdx.x;
  const int lane = tid & 63, wave = tid >> 6;
  constexpr int WM = BM / 2;
  constexpr int MI = WM / 16;
  constexpr int AIt = BM / 64;
  const int wm = (wave >> 1) * WM, wn = (wave & 1) * 64;
  const int quad = lane >> 4, l16 = lane & 15;
  const int lrow = lane >> 2;
  const int lcol = (lane & 3) * 8;

  floatx4 acc[MI][4] = {};

  auto issue = [&](int buf, int k0) {
#pragma unroll
    for (int t = 0; t < AIt; t++) {
      int is = wave * AIt + t;
      g2l16(A + (long long)(m0 + is * 16 + lrow) * lda + k0 + lcol, &Ash[buf][is * 16 * BK]);
    }
#pragma unroll
    for (int t = 0; t < 2; t++) {
      int is = wave * 2 + t;
      g2l16(B + (long long)(n0 + is * 16 + lrow) * ldb + k0 + lcol, &Bsh[buf][is * 16 * BK]);
    }
  };

  auto compute = [&](int buf) {
    half8 af[MI], bf[4];
#pragma unroll
    for (int i = 0; i < MI; i++)
      af[i] = *(const half8*)&Ash[buf][(wm + 16 * i + l16) * BK + quad * 8];
#pragma unroll
    for (int i = 0; i < 4; i++)
      bf[i] = *(const half8*)&Bsh[buf][(wn + 16 * i + l16) * BK + quad * 8];
#pragma unroll
    for (int mi = 0; mi < MI; mi++)
#pragma unroll
      for (int ni = 0; ni < 4; ni++)
        acc[mi][ni] = __builtin_amdgcn_mfma_f32_16x16x32_f16(af[mi], bf[ni], acc[mi][ni], 0, 0, 0);
  };

  issue(0, 0);
  for (int k0 = 0; k0 < K; k0 += 2 * BK) {
    __syncthreads();
    if (k0 + BK < K) issue(1, k0 + BK);
    compute(0);
    __syncthreads();
    if (k0 + 2 * BK < K) issue(0, k0 + 2 * BK);
    compute(1);
  }

  // C/D layout (m89-verified): row(m) = quad*4 + reg, col(n) = lane&15
#pragma unroll
  for (int ni = 0; ni < 4; ni++) {
    const int n = n0 + wn + 16 * ni + l16;
    float bv = 0.0f;
    if constexpr (MODE == 1) bv = bias[n];
#pragma unroll
    for (int mi = 0; mi < MI; mi++) {
      const int mg = m0 + wm + 16 * mi + quad * 4;
#pragma unroll
      for (int rr = 0; rr < 4; rr++) {
        float v = acc[mi][ni][rr] + bv;
        if constexpr (MODE == 1) {
          int m = mg + rr;
          if (n < 512) oq[m * 512 + n] = (_Float16)v;
          else if (n < 1024) ok[m * 512 + (n - 512)] = (_Float16)v;
          else ov[(n - 1024) * 16384 + m] = (_Float16)v;  // V^T
        } else {
          C[(long long)(mg + rr) * ldo + n] = (OutT)v;
        }
      }
    }
  }
}

// ---- fused flash attention: out = softmax(q k^T) v ----
// Grid 256 = 8 batches (XCD-pinned, i&7) x 32 Q-tiles of 64 rows. 8 waves.
// Qs [64][512] LDS (swizzled, staged once). 4 KV-steps of 512 keys:
//   QK: wave w -> S[64 rows][keys 512t+64w..+64], MI4 x NI4 outer product,
//       K-frags direct from L2 (k16 batch slice, 2 MB, XCD-resident).
//   stats: row-max via l16-shfl -> pm[64][8] -> combine (tid<64) -> cm/ca.
//   exp + P~ write to Ps [64][512] (slot-XOR swizzled), partial sums -> pl,
//   O-rescale by ca. Running sm/sl updated by tid<64.
//   PV: wave w -> O[64 rows][cols 64w..+64] += P~ @ V, P-frags from Ps,
//       V-frags direct from L2 (vt[col][key], exact B-operand layout).
// Epilogue: O / sl -> out fp32.
__global__ __launch_bounds__(512, 2) void attn_fused(const _Float16* __restrict__ q16,
                                                     const _Float16* __restrict__ k16,
                                                     const _Float16* __restrict__ vt,
                                                     float* __restrict__ out) {
  __shared__ _Float16 Qs[64 * 512];   // 64 KB
  __shared__ _Float16 Ps[64 * 512];   // 64 KB
  __shared__ float pm[64][8];
  __shared__ float pl[64][8];
  __shared__ float cm[64], ca[64], sm[64], sl[64];

  const unsigned bi = blockIdx.x;
  const int bz = bi & 7;              // batch -> XCD
  const int rb = bi >> 3;             // Q-tile 0..31
  const int tid = threadIdx.x;
  const int lane = tid & 63, wave = tid >> 6;
  const int l16 = lane & 15, quad = lane >> 4;

  const _Float16* qb = q16 + ((long long)bz * 2048 + rb * 64) * 512;
  const _Float16* kb = k16 + (long long)bz * 2048 * 512;
  const _Float16* vb = vt + (long long)bz * 2048;   // + col*16384 + key

  // stage Q (8 rows/wave), source pre-swizzled: LDS slot s of row r holds
  // global slot s^(r&7)  [R4-proven pattern]
#pragma unroll
  for (int r = 0; r < 8; r++) {
    int row = wave * 8 + r;
    g2l16(qb + row * 512 + ((lane ^ (row & 7)) * 8), &Qs[row * 512]);
  }
  if (tid < 64) { sm[tid] = -3.0e38f; sl[tid] = 0.0f; }
  VMCNT(0);
  __syncthreads();

  floatx4 accO[4][4] = {};  // O[16mi+quad*4+rr][64*wave+16ni+l16]

  for (int t = 0; t < 4; t++) {
    const long long keyBase = (long long)t * 512 + 64 * wave;
    // ---- QK: S-subtile [64 rows][64 keys] ----
    floatx4 accS[4][4] = {};
#pragma unroll
    for (int ks = 0; ks < 16; ks++) {
      half8 bfr[4];
#pragma unroll
      for (int ni = 0; ni < 4; ni++)
        bfr[ni] = *(const half8*)(kb + (keyBase + 16 * ni + l16) * 512 + ks * 32 + quad * 8);
      half8 afr[4];
#pragma unroll
      for (int mi = 0; mi < 4; mi++)
        afr[mi] = *(const half8*)&Qs[(16 * mi + l16) * 512 + (((ks * 4 + quad) ^ (l16 & 7)) * 8)];
#pragma unroll
      for (int mi = 0; mi < 4; mi++)
#pragma unroll
        for (int ni = 0; ni < 4; ni++)
          accS[mi][ni] = __builtin_amdgcn_mfma_f32_16x16x32_f16(afr[mi], bfr[ni], accS[mi][ni], 0, 0, 0);
    }
    // ---- per-row tile max over this wave's 64 keys ----
#pragma unroll
    for (int mi = 0; mi < 4; mi++)
#pragma unroll
      for (int rr = 0; rr < 4; rr++) {
        float v = fmaxf(fmaxf(accS[mi][0][rr], accS[mi][1][rr]),
                        fmaxf(accS[mi][2][rr], accS[mi][3][rr]));
#pragma unroll
        for (int o = 8; o >= 1; o >>= 1) v = fmaxf(v, __shfl_xor(v, o));
        if (l16 == 0) pm[16 * mi + quad * 4 + rr][wave] = v;
      }
    __syncthreads();  // B1: pm visible
    if (tid < 64) {
      float mo = sm[tid], mn = mo;
#pragma unroll
      for (int w = 0; w < 8; w++) mn = fmaxf(mn, pm[tid][w]);
      cm[tid] = mn;
      ca[tid] = __expf(mo - mn);
    }
    __syncthreads();  // B1b: cm/ca visible
    // ---- exp + P~ write + partial sums + O rescale ----
    float mrow[4][4], arow[4][4], psum[4][4];
#pragma unroll
    for (int mi = 0; mi < 4; mi++)
#pragma unroll
      for (int rr = 0; rr < 4; rr++) {
        int row = 16 * mi + quad * 4 + rr;
        mrow[mi][rr] = cm[row];
        arow[mi][rr] = ca[row];
        psum[mi][rr] = 0.0f;
      }
#pragma unroll
    for (int mi = 0; mi < 4; mi++)
#pragma unroll
      for (int ni = 0; ni < 4; ni++)
#pragma unroll
        for (int rr = 0; rr < 4; rr++) {
          int row = 16 * mi + quad * 4 + rr;
          float p = __expf(accS[mi][ni][rr] - mrow[mi][rr]);
          psum[mi][rr] += p;
          int slot = (8 * wave + 2 * ni + (l16 >> 3)) ^ (row & 7);
          Ps[row * 512 + slot * 8 + (l16 & 7)] = (_Float16)p;
        }
#pragma unroll
    for (int mi = 0; mi < 4; mi++)
#pragma unroll
      for (int rr = 0; rr < 4; rr++) {
        float v = psum[mi][rr];
#pragma unroll
        for (int o = 8; o >= 1; o >>= 1) v += __shfl_xor(v, o);
        if (l16 == 0) pl[16 * mi + quad * 4 + rr][wave] = v;
#pragma unroll
        for (int ni = 0; ni < 4; ni++) accO[mi][ni][rr] *= arow[mi][rr];
      }
    __syncthreads();  // B2: Ps + pl visible
    if (tid < 64) {
      float s = sl[tid] * ca[tid];
#pragma unroll
      for (int w = 0; w < 8; w++) s += pl[tid][w];
      sl[tid] = s;
      sm[tid] = cm[tid];
    }
    // ---- PV: O[64 rows][64 cols] += P~[64][512] @ V ----
#pragma unroll
    for (int ks = 0; ks < 16; ks++) {
      half8 vfr[4];
#pragma unroll
      for (int ni = 0; ni < 4; ni++)
        vfr[ni] = *(const half8*)(vb + (long long)(64 * wave + 16 * ni + l16) * 16384 +
                                  t * 512 + ks * 32 + quad * 8);
      half8 pfr[4];
#pragma unroll
      for (int mi = 0; mi < 4; mi++)
        pfr[mi] = *(const half8*)&Ps[(16 * mi + l16) * 512 + (((ks * 4 + quad) ^ (l16 & 7)) * 8)];
#pragma unroll
      for (int mi = 0; mi < 4; mi++)
#pragma unroll
        for (int ni = 0; ni < 4; ni++)
          accO[mi][ni] = __builtin_amdgcn_mfma_f32_16x16x32_f16(pfr[mi], vfr[ni], accO[mi][ni], 0, 0, 0);
    }
    __syncthreads();  // B3: Ps reads done before next t's writes; sl/sm visible
  }

  // ---- epilogue: O / sl ----
  float inv[4][4];
#pragma unroll
  for (int mi = 0; mi < 4; mi++)
#pragma unroll
    for (int rr = 0; rr < 4; rr++) inv[mi][rr] = 1.0f / sl[16 * mi + quad * 4 + rr];
  float* ob = out + ((long long)bz * 2048 + rb * 64) * 512;
#pragma unroll
  for (int mi = 0; mi < 4; mi++)
#pragma unroll
    for (int ni = 0; ni < 4; ni++)
#pragma unroll
      for (int rr = 0; rr < 4; rr++)
        ob[(long long)(16 * mi + quad * 4 + rr) * 512 + 64 * wave + 16 * ni + l16] =
            accO[mi][ni][rr] * inv[mi][rr];
}

// ---- softmax over f16 rows of S (2048 wide) — small-ws fallback only ----
__global__ __launch_bounds__(256) void softmax_kernel(_Float16* __restrict__ S) {
  const int lane = threadIdx.x & 63;
  const int wave = threadIdx.x >> 6;
  const long long row = (long long)blockIdx.x * 4 + wave;
  _Float16* srow = S + row * 2048;
  float v[32];
  float mx = -3.4e38f;
#pragma unroll
  for (int pass = 0; pass < 4; pass++) {
    half8 f = *(const half8*)(srow + (pass * 64 + lane) * 8);
#pragma unroll
    for (int j = 0; j < 8; j++) {
      float x = (float)f[j];
      v[pass * 8 + j] = x;
      mx = fmaxf(mx, x);
    }
  }
#pragma unroll
  for (int o = 32; o > 0; o >>= 1) mx = fmaxf(mx, __shfl_xor(mx, o));
  float sum = 0.0f;
#pragma unroll
  for (int j = 0; j < 32; j++) {
    v[j] = __expf(v[j] - mx);
    sum += v[j];
  }
#pragma unroll
  for (int o = 32; o > 0; o >>= 1) sum += __shfl_xor(sum, o);
  const float inv = 1.0f / sum;
#pragma unroll
  for (int pass = 0; pass < 4; pass++) {
    half8 o8;
#pragma unroll
    for (int j = 0; j < 8; j++) o8[j] = (_Float16)(v[pass * 8 + j] * inv);
    *(half8*)(srow + (pass * 64 + lane) * 8) = o8;
  }
}

extern "C" void kernel_launch(void* const* d_in, const int* in_sizes, int n_in,
                              void* d_out, int out_size, void* d_ws, size_t ws_size,
                              hipStream_t stream) {
  const float* e  = (const float*)d_in[0];
  const float* Wq = (const float*)d_in[1];
  const float* bq = (const float*)d_in[2];
  const float* Wk = (const float*)d_in[3];
  const float* bk = (const float*)d_in[4];
  const float* Wv = (const float*)d_in[5];
  const float* bv = (const float*)d_in[6];
  float* out = (float*)d_out;
  char* ws = (char*)d_ws;

  const long long MiB = 1024LL * 1024LL;
  const bool big = ws_size >= (size_t)(115 * MiB);
  const long long base = big ? 64 * MiB : 16 * MiB;  // x16 needs 16 MiB at head

  _Float16* S    = (_Float16*)ws;  // small-ws fallback only
  _Float16* x16  = (_Float16*)ws;  // overlays S head; dead before S written
  _Float16* q16  = (_Float16*)(ws + base);
  _Float16* k16  = (_Float16*)(ws + base + 16 * MiB);
  _Float16* vt   = (_Float16*)(ws + base + 32 * MiB);
  _Float16* wcat = (_Float16*)(ws + base + 48 * MiB);   // 1.5 MiB
  float*    bcat = (float*)(ws + base + 48 * MiB + 1536 * 1024);

  prep_cvt_kernel<<<11264, 256, 0, stream>>>(e, x16, Wq, Wk, Wv, bq, bk, bv, wcat, bcat);

  // fused QKV: M=16384 N=1536 K=512; R0-proven gemm6<128>; q/k plain, v^T
  gemm6<128, _Float16, 1, 0><<<1536, 256, 0, stream>>>(
      x16, wcat, bcat, (_Float16*)nullptr, 512, 512, 0, 512, 0, 0, 0, q16, k16, vt);

  if (big) {
    // fused flash attention: 256 blocks (8 batch x 32 Q-tiles), 8 waves
    attn_fused<<<256, 512, 0, stream>>>(q16, k16, vt, out);
  } else {
    for (int b = 0; b < 8; b++) {
      gemm6<128, _Float16, 0, 0><<<dim3(16, 16, 1), 256, 0, stream>>>(
          q16 + (long long)b * 1048576, k16 + (long long)b * 1048576, nullptr, S,
          512, 512, 2048, 512, 0, 0, 0, nullptr, nullptr, nullptr);
      softmax_kernel<<<512, 256, 0, stream>>>(S);
      gemm6<64, float, 0, 0><<<dim3(4, 32, 1), 256, 0, stream>>>(
          S, vt + (long long)b * 2048, nullptr, out + (long long)b * 1048576,
          2048, 16384, 512, 2048, 0, 0, 0, nullptr, nullptr, nullptr);
    }
  }
}

// Round 8
// 270.270 us; speedup vs baseline: 1.2650x; 1.2650x over previous
//
#include <hip/hip_runtime.h>
#include <hip/hip_fp16.h>

// MSAAttention: x = e + PE; q,k,v = Linear(x); out = softmax(q k^T) v
// B=8 S=2048 H=512, fp32 in/out. f16 MFMA GEMMs + fp32-math softmax.
//
// Round 14 = R5 (best, 266.5) + two bounded changes:
//  1. QKV moves to gemm9<128,256,MODE1>, grid 768 = 3 CLEAN rounds at
//     1 block/CU. R3's QKV-gemm9 loss is attributed to its 384-block grid
//     (1.5 rounds -> half-utilized 2nd round), not the schedule; the
//     <128,256> instantiation is PV-validated, the MODE1 epilogue is
//     R3-correctness-validated.
//  2. PE table: pe16[2048][512] built once (1/8 the trig, L2-resident),
//     prep becomes pure streaming add+cvt.
// Everything else identical to R5: S = gemm9 256^2 (512 blocks), softmax,
// PV = gemm9 128x256 (256 blocks), gemm6 kept for the small-ws path.

using half8   = __attribute__((ext_vector_type(8))) _Float16;
using half4v  = __attribute__((ext_vector_type(4))) _Float16;
using floatx4 = __attribute__((ext_vector_type(4))) float;

#define BK 32  // halves per K chunk -> 64 B LDS rows (gemm6)

#define VMCNT(N) asm volatile("s_waitcnt vmcnt(" #N ")" ::: "memory")

__device__ __forceinline__ void g2l16(const void* g, void* l) {
  // async global->LDS DMA, 16 B/lane; LDS dest = wave-uniform base + lane*16
  __builtin_amdgcn_global_load_lds((const __attribute__((address_space(1))) void*)g,
                                   (__attribute__((address_space(3))) void*)l, 16, 0, 0);
}

// ---- pe_build: pe16[s][h] = h<256 ? sin(s*div[h]) : cos(s*div[h-256]) ----
__global__ __launch_bounds__(256) void pe_build(_Float16* __restrict__ pe) {
  int i = blockIdx.x * 256 + threadIdx.x;  // 262144 threads, 4 elems each
  int idx = i * 4;
  int h = idx & 511;
  int s = idx >> 9;
  const float ks = -9.210340371976184f / 256.0f;  // -ln(10000)/256
  half4v o;
#pragma unroll
  for (int j = 0; j < 4; j++) {
    int hh = h + j;
    int ii = (hh < 256) ? hh : (hh - 256);
    float ang = (float)s * __expf((float)ii * ks);
    o[j] = (_Float16)((hh < 256) ? __sinf(ang) : __cosf(ang));
  }
  *(half4v*)(pe + idx) = o;
}

// ---- prep (blocks 0..8191): x16 = f16(embeds + PE[table])
// ---- cvt  (blocks 8192..11263): wcat f16 [1536][512] + bcat fp32 [1536]
__global__ __launch_bounds__(256) void prep_cvt_kernel(const float* __restrict__ e,
                                                       const _Float16* __restrict__ pe,
                                                       _Float16* __restrict__ x16,
                                                       const float* __restrict__ wq,
                                                       const float* __restrict__ wk,
                                                       const float* __restrict__ wv,
                                                       const float* __restrict__ bq,
                                                       const float* __restrict__ bk,
                                                       const float* __restrict__ bv,
                                                       _Float16* __restrict__ wcat,
                                                       float* __restrict__ bcat) {
  if (blockIdx.x < 8192) {
    int t = blockIdx.x * 256 + threadIdx.x;  // 2M threads, 4 elems each
    int idx = t * 4;
    float4 ev = *(const float4*)(e + idx);
    half4v pv = *(const half4v*)(pe + (idx & 1048575));  // idx mod 2048*512
    half4v o = {(_Float16)(ev.x + (float)pv[0]), (_Float16)(ev.y + (float)pv[1]),
                (_Float16)(ev.z + (float)pv[2]), (_Float16)(ev.w + (float)pv[3])};
    *(half4v*)(x16 + idx) = o;
  } else {
    int i = (blockIdx.x - 8192) * 256 + threadIdx.x;  // 786432
    int m = i & 262143;
    const float* s = (i < 262144) ? wq : (i < 524288) ? wk : wv;
    wcat[i] = (_Float16)s[m];
    if (i < 512) bcat[i] = bq[i];
    else if (i < 1024) bcat[i] = bk[i - 512];
    else if (i < 1536) bcat[i] = bv[i - 1024];
  }
}

// ---- gemm6 (R0-proven 2-phase): small-ws fallback path ----
// A [M,K] lda, B [N,K] ldb, k-contiguous. Tile BM x 128, BK=32, 4 waves (2x2).
template <int BM, typename OutT, int MODE, int LBX>
__global__ __launch_bounds__(256) void gemm6(const _Float16* __restrict__ A,
                                             const _Float16* __restrict__ B,
                                             const float* __restrict__ bias,
                                             OutT* __restrict__ C,
                                             int lda, int ldb, int ldo, int K,
                                             long long sA, long long sB, long long sC,
                                             _Float16* __restrict__ oq,
                                             _Float16* __restrict__ ok,
                                             _Float16* __restrict__ ov) {
  __shared__ _Float16 Ash[2][BM * BK];
  __shared__ _Float16 Bsh[2][128 * BK];
  int bx, by, bz;
  if constexpr (MODE == 1) {
    constexpr int BYX = 2048 / BM;
    unsigned i = blockIdx.x;
    unsigned c = i & 7, j = i >> 3;
    by = c * BYX + j / 12;
    bx = j % 12;
    bz = 0;
  } else if constexpr (MODE == 2) {
    unsigned i = blockIdx.x;
    unsigned c = i & 7, j = i >> 3;
    bz = c;
    bx = j & ((1u << LBX) - 1);
    by = j >> LBX;
  } else {
    bx = blockIdx.x; by = blockIdx.y; bz = blockIdx.z;
  }
  A += (long long)bz * sA;
  B += (long long)bz * sB;
  C += (long long)bz * sC;
  const int m0 = by * BM, n0 = bx * 128;
  const int tid = threadIdx.x;
  const int lane = tid & 63, wave = tid >> 6;
  constexpr int WM = BM / 2;
  constexpr int MI = WM / 16;
  constexpr int AIt = BM / 64;
  const int wm = (wave >> 1) * WM, wn = (wave & 1) * 64;
  const int quad = lane >> 4, l16 = lane & 15;
  const int lrow = lane >> 2;
  const int lcol = (lane & 3) * 8;

  floatx4 acc[MI][4] = {};

  auto issue = [&](int buf, int k0) {
#pragma unroll
    for (int t = 0; t < AIt; t++) {
      int is = wave * AIt + t;
      g2l16(A + (long long)(m0 + is * 16 + lrow) * lda + k0 + lcol, &Ash[buf][is * 16 * BK]);
    }
#pragma unroll
    for (int t = 0; t < 2; t++) {
      int is = wave * 2 + t;
      g2l16(B + (long long)(n0 + is * 16 + lrow) * ldb + k0 + lcol, &Bsh[buf][is * 16 * BK]);
    }
  };

  auto compute = [&](int buf) {
    half8 af[MI], bf[4];
#pragma unroll
    for (int i = 0; i < MI; i++)
      af[i] = *(const half8*)&Ash[buf][(wm + 16 * i + l16) * BK + quad * 8];
#pragma unroll
    for (int i = 0; i < 4; i++)
      bf[i] = *(const half8*)&Bsh[buf][(wn + 16 * i + l16) * BK + quad * 8];
#pragma unroll
    for (int mi = 0; mi < MI; mi++)
#pragma unroll
      for (int ni = 0; ni < 4; ni++)
        acc[mi][ni] = __builtin_amdgcn_mfma_f32_16x16x32_f16(af[mi], bf[ni], acc[mi][ni], 0, 0, 0);
  };

  issue(0, 0);
  for (int k0 = 0; k0 < K; k0 += 2 * BK) {
    __syncthreads();
    if (k0 + BK < K) issue(1, k0 + BK);
    compute(0);
    __syncthreads();
    if (k0 + 2 * BK < K) issue(0, k0 + 2 * BK);
    compute(1);
  }

  // C/D layout (m89-verified): row(m) = quad*4 + reg, col(n) = lane&15
#pragma unroll
  for (int ni = 0; ni < 4; ni++) {
    const int n = n0 + wn + 16 * ni + l16;
    float bv = 0.0f;
    if constexpr (MODE == 1) bv = bias[n];
#pragma unroll
    for (int mi = 0; mi < MI; mi++) {
      const int mg = m0 + wm + 16 * mi + quad * 4;
#pragma unroll
      for (int rr = 0; rr < 4; rr++) {
        float v = acc[mi][ni][rr] + bv;
        if constexpr (MODE == 1) {
          int m = mg + rr;
          if (n < 512) oq[m * 512 + n] = (_Float16)v;
          else if (n < 1024) ok[m * 512 + (n - 512)] = (_Float16)v;
          else ov[(n - 1024) * 16384 + m] = (_Float16)v;  // V^T
        } else {
          C[(long long)(mg + rr) * ldo + n] = (OutT)v;
        }
      }
    }
  }
}

// ---- gemm9 (R3-proven 8-phase): deep-pipelined f16 MFMA GEMM ----
// Tile BM x BN, BK=64, 8 waves (2M x 4N), per-wave (BM/2) x (BN/4).
// LDS: [2 bufs][2 kk-halves][rows][32 halves]; each kk-half contiguous.
// Counted vmcnt(IA+IB) once per tile; vmcnt(0) only last 2 tiles. XOR-
// swizzled LDS reads with inverse swizzle on the staging source. setprio(1)
// around MFMA clusters.
// MODE 1: QKV — M=16384 N=1536, grid 8*(16384/BM/8)*(1536/BN), XCD decode,
//         bias + q/k plain, v transposed.
// MODE 2: 1D grid, bz = id&7 (batch->XCD), bx = j & (2^LBX-1).
template <int BM, int BN, typename OutT, int MODE, int LBX>
__global__ __launch_bounds__(512, 2) void gemm9(const _Float16* __restrict__ A,
                                                const _Float16* __restrict__ B,
                                                const float* __restrict__ bias,
                                                OutT* __restrict__ C,
                                                int lda, int ldb, int ldo, int K,
                                                long long sA, long long sB, long long sC,
                                                _Float16* __restrict__ oq,
                                                _Float16* __restrict__ ok,
                                                _Float16* __restrict__ ov) {
  constexpr int MI = BM / 32;   // per-wave m-frags
  constexpr int NI = BN / 64;   // per-wave n-frags
  constexpr int NIH = NI / 2;
  constexpr int IA = BM / 128;  // gload issues / wave / A-half
  constexpr int IB = BN / 128;

  __shared__ _Float16 Ash[2][2][BM * 32];
  __shared__ _Float16 Bsh[2][2][BN * 32];

  int bx, by, bz;
  if constexpr (MODE == 1) {
    constexpr int NBX = 1536 / BN;          // bx-tiles
    constexpr int BYX = 16384 / BM / 8;     // by-tiles per XCD
    unsigned i = blockIdx.x;                // 8 * BYX * NBX blocks
    unsigned c = i & 7, j = i >> 3;
    by = c * BYX + j / NBX;                 // XCD c owns contiguous by-range
    bx = j % NBX;
    bz = 0;
  } else {
    unsigned i = blockIdx.x;
    unsigned c = i & 7, j = i >> 3;
    bz = c;                          // batch -> XCD: operands L2-resident
    bx = j & ((1u << LBX) - 1);
    by = j >> LBX;
  }
  A += (long long)bz * sA;
  B += (long long)bz * sB;
  C += (long long)bz * sC;
  const int m0 = by * BM, n0 = bx * BN;
  const int tid = threadIdx.x;
  const int lane = tid & 63, wave = tid >> 6;
  const int l16 = lane & 15, quad = lane >> 4;
  const int wrow = (wave >> 2) * (BM / 2);
  const int wcol = (wave & 3) * (BN / 4);
  const int srow = lane >> 2;                              // staging row in issue
  const int scol = 8 * ((lane & 3) ^ ((lane >> 3) & 3));   // inverse-swizzled col
  const int rsw = (l16 >> 1) & 3;                          // read-side swizzle

  // staging source base pointers (k-invariant)
  const _Float16* aSrc[IA];
  const _Float16* bSrc[IB];
#pragma unroll
  for (int i = 0; i < IA; i++)
    aSrc[i] = A + (long long)(m0 + (wave * IA + i) * 16 + srow) * lda + scol;
#pragma unroll
  for (int i = 0; i < IB; i++)
    bSrc[i] = B + (long long)(n0 + (wave * IB + i) * 16 + srow) * ldb + scol;

  auto stA = [&](int tile, int kk) {
#pragma unroll
    for (int i = 0; i < IA; i++)
      g2l16(aSrc[i] + tile * 64 + kk * 32,
            (_Float16*)Ash[tile & 1][kk] + (wave * IA + i) * 512);
  };
  auto stB = [&](int tile, int kk) {
#pragma unroll
    for (int i = 0; i < IB; i++)
      g2l16(bSrc[i] + tile * 64 + kk * 32,
            (_Float16*)Bsh[tile & 1][kk] + (wave * IB + i) * 512);
  };

  floatx4 acc[MI][NI] = {};
  half8 af[MI], bf[NI];

  auto ldA = [&](int buf, int kk) {
#pragma unroll
    for (int mi = 0; mi < MI; mi++)
      af[mi] = *(const half8*)(Ash[buf][kk] + (wrow + mi * 16 + l16) * 32 + (quad ^ rsw) * 8);
  };
  auto ldB0 = [&](int buf, int kk) {
#pragma unroll
    for (int j = 0; j < NIH; j++)
      bf[j] = *(const half8*)(Bsh[buf][kk] + (wcol + j * 16 + l16) * 32 + (quad ^ rsw) * 8);
  };
  auto ldB1 = [&](int buf, int kk) {
#pragma unroll
    for (int j = 0; j < NIH; j++)
      bf[NIH + j] = *(const half8*)(Bsh[buf][kk] + (wcol + (NIH + j) * 16 + l16) * 32 + (quad ^ rsw) * 8);
  };
  auto mm0 = [&]() {
#pragma unroll
    for (int mi = 0; mi < MI; mi++)
#pragma unroll
      for (int j = 0; j < NIH; j++)
        acc[mi][j] = __builtin_amdgcn_mfma_f32_16x16x32_f16(af[mi], bf[j], acc[mi][j], 0, 0, 0);
  };
  auto mm1 = [&]() {
#pragma unroll
    for (int mi = 0; mi < MI; mi++)
#pragma unroll
      for (int j = 0; j < NIH; j++)
        acc[mi][NIH + j] =
            __builtin_amdgcn_mfma_f32_16x16x32_f16(af[mi], bf[NIH + j], acc[mi][NIH + j], 0, 0, 0);
  };

#define MFMA_SEG(MMX)                                 \
  __builtin_amdgcn_s_barrier();                       \
  asm volatile("s_waitcnt lgkmcnt(0)" ::: "memory");  \
  __builtin_amdgcn_sched_barrier(0);                  \
  __builtin_amdgcn_s_setprio(1);                      \
  MMX();                                              \
  __builtin_amdgcn_s_setprio(0);                      \
  __builtin_amdgcn_sched_barrier(0);                  \
  __builtin_amdgcn_s_barrier();

  const int NT = K / 64;
  // prologue: tile0 complete + tile1 kk0 halves (FIFO order matters)
  stA(0, 0); stB(0, 0); stA(0, 1); stB(0, 1); stA(1, 0); stB(1, 0);
  if constexpr (IA + IB == 4) { VMCNT(4); } else { VMCNT(3); }
  __builtin_amdgcn_s_barrier();

  for (int t = 0; t < NT; ++t) {
    const int buf = t & 1;
    const bool s1 = (t + 1 < NT), s2 = (t + 2 < NT);
    // p1 (kk0, n-lo) | stage A1[t+1] (other buf, region dead since t-1 p4)
    ldA(buf, 0); ldB0(buf, 0);
    if (s1) stA(t + 1, 1);
    MFMA_SEG(mm0);
    // p2 (kk0, n-hi) | stage B1[t+1]
    ldB1(buf, 0);
    if (s1) stB(t + 1, 1);
    MFMA_SEG(mm1);
    // p3 (kk1, n-lo) | stage A0[t+2] (this buf, region dead since p2)
    ldA(buf, 1); ldB0(buf, 1);
    if (s2) stA(t + 2, 0);
    MFMA_SEG(mm0);
    // p4 (kk1, n-hi) | stage B0[t+2]; counted vmcnt covers next tile's reads
    ldB1(buf, 1);
    if (s2) stB(t + 2, 0);
    if (t < NT - 2) {
      if constexpr (IA + IB == 4) { VMCNT(4); } else { VMCNT(3); }
    } else {
      VMCNT(0);
    }
    MFMA_SEG(mm1);
  }
#undef MFMA_SEG

  // C/D layout (m89-verified): row(m) = quad*4 + reg, col(n) = lane&15
#pragma unroll
  for (int ni = 0; ni < NI; ni++) {
    const int n = n0 + wcol + 16 * ni + l16;
    float bv = 0.0f;
    if constexpr (MODE == 1) bv = bias[n];
#pragma unroll
    for (int mi = 0; mi < MI; mi++) {
      const int mg = m0 + wrow + 16 * mi + quad * 4;
#pragma unroll
      for (int rr = 0; rr < 4; rr++) {
        float v = acc[mi][ni][rr] + bv;
        if constexpr (MODE == 1) {
          int m = mg + rr;
          if (n < 512) oq[m * 512 + n] = (_Float16)v;
          else if (n < 1024) ok[m * 512 + (n - 512)] = (_Float16)v;
          else ov[(n - 1024) * 16384 + m] = (_Float16)v;  // V^T
        } else {
          C[(long long)(mg + rr) * ldo + n] = (OutT)v;
        }
      }
    }
  }
}

// ---- softmax over f16 rows of S (2048 wide), fp32 math, f16 in place ----
__global__ __launch_bounds__(256) void softmax_kernel(_Float16* __restrict__ S) {
  const int lane = threadIdx.x & 63;
  const int wave = threadIdx.x >> 6;
  const long long row = (long long)blockIdx.x * 4 + wave;
  _Float16* srow = S + row * 2048;
  float v[32];
  float mx = -3.4e38f;
#pragma unroll
  for (int pass = 0; pass < 4; pass++) {
    half8 f = *(const half8*)(srow + (pass * 64 + lane) * 8);
#pragma unroll
    for (int j = 0; j < 8; j++) {
      float x = (float)f[j];
      v[pass * 8 + j] = x;
      mx = fmaxf(mx, x);
    }
  }
#pragma unroll
  for (int o = 32; o > 0; o >>= 1) mx = fmaxf(mx, __shfl_xor(mx, o));
  float sum = 0.0f;
#pragma unroll
  for (int j = 0; j < 32; j++) {
    v[j] = __expf(v[j] - mx);
    sum += v[j];
  }
#pragma unroll
  for (int o = 32; o > 0; o >>= 1) sum += __shfl_xor(sum, o);
  const float inv = 1.0f / sum;
#pragma unroll
  for (int pass = 0; pass < 4; pass++) {
    half8 o8;
#pragma unroll
    for (int j = 0; j < 8; j++) o8[j] = (_Float16)(v[pass * 8 + j] * inv);
    *(half8*)(srow + (pass * 64 + lane) * 8) = o8;
  }
}

extern "C" void kernel_launch(void* const* d_in, const int* in_sizes, int n_in,
                              void* d_out, int out_size, void* d_ws, size_t ws_size,
                              hipStream_t stream) {
  const float* e  = (const float*)d_in[0];
  const float* Wq = (const float*)d_in[1];
  const float* bq = (const float*)d_in[2];
  const float* Wk = (const float*)d_in[3];
  const float* bk = (const float*)d_in[4];
  const float* Wv = (const float*)d_in[5];
  const float* bv = (const float*)d_in[6];
  float* out = (float*)d_out;
  char* ws = (char*)d_ws;

  const long long MiB = 1024LL * 1024LL;
  // big: S f16 [8][2048][2048] = 64 MiB at once; small: per-batch 8 MiB
  const bool big = ws_size >= (size_t)(115 * MiB);
  const long long base = big ? 64 * MiB : 16 * MiB;  // x16 needs 16 MiB at head

  _Float16* S    = (_Float16*)ws;
  _Float16* x16  = (_Float16*)ws;              // [0,16 MiB); dead before S written
  _Float16* pe16 = (_Float16*)(ws + 16 * MiB); // [16,18 MiB); dead after prep
  _Float16* q16  = (_Float16*)(ws + base);
  _Float16* k16  = (_Float16*)(ws + base + 16 * MiB);
  _Float16* vt   = (_Float16*)(ws + base + 32 * MiB);
  _Float16* wcat = (_Float16*)(ws + base + 48 * MiB);   // 1.5 MiB
  float*    bcat = (float*)(ws + base + 48 * MiB + 1536 * 1024);

  pe_build<<<1024, 256, 0, stream>>>(pe16);
  prep_cvt_kernel<<<11264, 256, 0, stream>>>(e, pe16, x16, Wq, Wk, Wv, bq, bk, bv, wcat, bcat);

  // fused QKV: M=16384 N=1536 K=512; gemm9 128x256, grid 768 = 3 clean
  // rounds at 1 block/CU; q/k plain, v transposed
  gemm9<128, 256, _Float16, 1, 0><<<768, 512, 0, stream>>>(
      x16, wcat, bcat, (_Float16*)nullptr, 512, 512, 0, 512, 0, 0, 0, q16, k16, vt);

  if (big) {
    // S = q k^T batched: M=N=2048 K=512 f16 out; 8-phase 256x256, grid 512
    gemm9<256, 256, _Float16, 2, 3><<<512, 512, 0, stream>>>(
        q16, k16, nullptr, S, 512, 512, 2048, 512,
        1048576LL, 1048576LL, 4194304LL, nullptr, nullptr, nullptr);
    softmax_kernel<<<4096, 256, 0, stream>>>(S);
    // out = P v: M=2048 N=512 K=2048; 8-phase 128x256, grid 256, NT=32
    gemm9<128, 256, float, 2, 1><<<256, 512, 0, stream>>>(
        S, vt, nullptr, out, 2048, 16384, 512, 2048,
        4194304LL, 2048LL, 1048576LL, nullptr, nullptr, nullptr);
  } else {
    for (int b = 0; b < 8; b++) {
      gemm6<128, _Float16, 0, 0><<<dim3(16, 16, 1), 256, 0, stream>>>(
          q16 + (long long)b * 1048576, k16 + (long long)b * 1048576, nullptr, S,
          512, 512, 2048, 512, 0, 0, 0, nullptr, nullptr, nullptr);
      softmax_kernel<<<512, 256, 0, stream>>>(S);
      gemm6<64, float, 0, 0><<<dim3(4, 32, 1), 256, 0, stream>>>(
          S, vt + (long long)b * 2048, nullptr, out + (long long)b * 1048576,
          2048, 16384, 512, 2048, 0, 0, 0, nullptr, nullptr, nullptr);
    }
  }
}

// Round 9
// 265.669 us; speedup vs baseline: 1.2869x; 1.0173x over previous
//
#include <hip/hip_runtime.h>
#include <hip/hip_fp16.h>

// MSAAttention: x = e + PE; q,k,v = Linear(x); out = softmax(q k^T) v
// B=8 S=2048 H=512, fp32 in/out. f16 MFMA GEMMs + fp32-math softmax.
//
// Round 15: best-of-measured recombination.
//  - QKV: gemm6<128> 2-phase, grid 1536 (66 us; beats gemm9 at 73/89 us on
//    this shape in R8/R3 -- 8-phase loses on the QKV geometry regardless of
//    grid rounding).
//  - PE table in FP32 (4 MB): keeps R8's ~3 us prep saving (1/8 the trig)
//    without the f16 double-rounding that pushed absmax 0.039->0.043.
//  - S = gemm9 256x256 grid 512, softmax, PV = gemm9 128x256 grid 256:
//    all R5-proven.
// Occupancy note (R8 post-mortem): gemm6's ~23% occupancy is VGPR-limited
// on the unified VGPR+AGPR file (72+64 regs -> ~2 blocks/CU); deeper
// pipelines can't help within that cap, which is why 2-phase wins here.

using half8   = __attribute__((ext_vector_type(8))) _Float16;
using half4v  = __attribute__((ext_vector_type(4))) _Float16;
using floatx4 = __attribute__((ext_vector_type(4))) float;

#define BK 32  // halves per K chunk -> 64 B LDS rows (gemm6)

#define VMCNT(N) asm volatile("s_waitcnt vmcnt(" #N ")" ::: "memory")

__device__ __forceinline__ void g2l16(const void* g, void* l) {
  // async global->LDS DMA, 16 B/lane; LDS dest = wave-uniform base + lane*16
  __builtin_amdgcn_global_load_lds((const __attribute__((address_space(1))) void*)g,
                                   (__attribute__((address_space(3))) void*)l, 16, 0, 0);
}

// ---- pe_build: pe[s][h] = h<256 ? sin(s*div[h]) : cos(s*div[h-256]) ----
__global__ __launch_bounds__(256) void pe_build(float* __restrict__ pe) {
  int i = blockIdx.x * 256 + threadIdx.x;  // 262144 threads, 4 elems each
  int idx = i * 4;
  int h = idx & 511;
  int s = idx >> 9;
  const float ks = -9.210340371976184f / 256.0f;  // -ln(10000)/256
  float4 o;
  float r[4];
#pragma unroll
  for (int j = 0; j < 4; j++) {
    int hh = h + j;
    int ii = (hh < 256) ? hh : (hh - 256);
    float ang = (float)s * __expf((float)ii * ks);
    r[j] = (hh < 256) ? __sinf(ang) : __cosf(ang);
  }
  o.x = r[0]; o.y = r[1]; o.z = r[2]; o.w = r[3];
  *(float4*)(pe + idx) = o;
}

// ---- prep (blocks 0..8191): x16 = f16(embeds + PE[table, f32])
// ---- cvt  (blocks 8192..11263): wcat f16 [1536][512] + bcat fp32 [1536]
__global__ __launch_bounds__(256) void prep_cvt_kernel(const float* __restrict__ e,
                                                       const float* __restrict__ pe,
                                                       _Float16* __restrict__ x16,
                                                       const float* __restrict__ wq,
                                                       const float* __restrict__ wk,
                                                       const float* __restrict__ wv,
                                                       const float* __restrict__ bq,
                                                       const float* __restrict__ bk,
                                                       const float* __restrict__ bv,
                                                       _Float16* __restrict__ wcat,
                                                       float* __restrict__ bcat) {
  if (blockIdx.x < 8192) {
    int t = blockIdx.x * 256 + threadIdx.x;  // 2M threads, 4 elems each
    int idx = t * 4;
    float4 ev = *(const float4*)(e + idx);
    float4 pv = *(const float4*)(pe + (idx & 1048575));  // idx mod 2048*512
    half4v o = {(_Float16)(ev.x + pv.x), (_Float16)(ev.y + pv.y),
                (_Float16)(ev.z + pv.z), (_Float16)(ev.w + pv.w)};
    *(half4v*)(x16 + idx) = o;
  } else {
    int i = (blockIdx.x - 8192) * 256 + threadIdx.x;  // 786432
    int m = i & 262143;
    const float* s = (i < 262144) ? wq : (i < 524288) ? wk : wv;
    wcat[i] = (_Float16)s[m];
    if (i < 512) bcat[i] = bq[i];
    else if (i < 1024) bcat[i] = bk[i - 512];
    else if (i < 1536) bcat[i] = bv[i - 1024];
  }
}

// ---- gemm6 (R0-proven 2-phase): C[m][n] = sum_k A[m][k]*B[n][k] ----
// A [M,K] lda, B [N,K] ldb, k-contiguous. Tile BM x 128, BK=32, 4 waves (2x2),
// wave tile (BM/2) x 64 via 16x16x32 frags. Double-buffered LDS, one barrier
// per K-step, next tile's DMA issued right after the barrier.
// MODE 0: plain 3D grid, plain store.
// MODE 1: QKV — 1D grid 8*(2048/BM)*12, XCD decode, bias + q/k plain, v^T.
// MODE 2: 1D grid, XCD decode bz = id&7 (batch->XCD), bx = j & (2^LBX - 1).
template <int BM, typename OutT, int MODE, int LBX>
__global__ __launch_bounds__(256) void gemm6(const _Float16* __restrict__ A,
                                             const _Float16* __restrict__ B,
                                             const float* __restrict__ bias,
                                             OutT* __restrict__ C,
                                             int lda, int ldb, int ldo, int K,
                                             long long sA, long long sB, long long sC,
                                             _Float16* __restrict__ oq,
                                             _Float16* __restrict__ ok,
                                             _Float16* __restrict__ ov) {
  __shared__ _Float16 Ash[2][BM * BK];
  __shared__ _Float16 Bsh[2][128 * BK];
  int bx, by, bz;
  if constexpr (MODE == 1) {
    constexpr int BYX = 2048 / BM;     // by-tiles per XCD (16384 rows / 8)
    unsigned i = blockIdx.x;
    unsigned c = i & 7, j = i >> 3;
    by = c * BYX + j / 12;             // XCD c owns contiguous by-range
    bx = j % 12;
    bz = 0;
  } else if constexpr (MODE == 2) {
    unsigned i = blockIdx.x;
    unsigned c = i & 7, j = i >> 3;
    bz = c;                            // batch -> XCD: operands L2-resident
    bx = j & ((1u << LBX) - 1);
    by = j >> LBX;
  } else {
    bx = blockIdx.x; by = blockIdx.y; bz = blockIdx.z;
  }
  A += (long long)bz * sA;
  B += (long long)bz * sB;
  C += (long long)bz * sC;
  const int m0 = by * BM, n0 = bx * 128;
  const int tid = threadIdx.x;
  const int lane = tid & 63, wave = tid >> 6;
  constexpr int WM = BM / 2;
  constexpr int MI = WM / 16;
  constexpr int AIt = BM / 64;  // A staging issues per wave (16 rows / issue)
  const int wm = (wave >> 1) * WM, wn = (wave & 1) * 64;
  const int quad = lane >> 4, l16 = lane & 15;
  const int lrow = lane >> 2;       // row within a 16-row staging issue
  const int lcol = (lane & 3) * 8;  // half offset within the 32-half row

  floatx4 acc[MI][4] = {};

  auto issue = [&](int buf, int k0) {
#pragma unroll
    for (int t = 0; t < AIt; t++) {
      int is = wave * AIt + t;
      g2l16(A + (long long)(m0 + is * 16 + lrow) * lda + k0 + lcol, &Ash[buf][is * 16 * BK]);
    }
#pragma unroll
    for (int t = 0; t < 2; t++) {
      int is = wave * 2 + t;
      g2l16(B + (long long)(n0 + is * 16 + lrow) * ldb + k0 + lcol, &Bsh[buf][is * 16 * BK]);
    }
  };

  auto compute = [&](int buf) {
    half8 af[MI], bf[4];
#pragma unroll
    for (int i = 0; i < MI; i++)
      af[i] = *(const half8*)&Ash[buf][(wm + 16 * i + l16) * BK + quad * 8];
#pragma unroll
    for (int i = 0; i < 4; i++)
      bf[i] = *(const half8*)&Bsh[buf][(wn + 16 * i + l16) * BK + quad * 8];
#pragma unroll
    for (int mi = 0; mi < MI; mi++)
#pragma unroll
      for (int ni = 0; ni < 4; ni++)
        acc[mi][ni] = __builtin_amdgcn_mfma_f32_16x16x32_f16(af[mi], bf[ni], acc[mi][ni], 0, 0, 0);
  };

  issue(0, 0);
  for (int k0 = 0; k0 < K; k0 += 2 * BK) {
    __syncthreads();                       // drains tile-k DMA (issued one step ago)
    if (k0 + BK < K) issue(1, k0 + BK);    // prefetch flies during compute(0)
    compute(0);
    __syncthreads();                       // ds_reads of buf0 done; drains buf1 DMA
    if (k0 + 2 * BK < K) issue(0, k0 + 2 * BK);
    compute(1);
  }

  // C/D layout (m89-verified): row(m) = quad*4 + reg, col(n) = lane&15
#pragma unroll
  for (int ni = 0; ni < 4; ni++) {
    const int n = n0 + wn + 16 * ni + l16;
    float bv = 0.0f;
    if constexpr (MODE == 1) bv = bias[n];
#pragma unroll
    for (int mi = 0; mi < MI; mi++) {
      const int mg = m0 + wm + 16 * mi + quad * 4;
#pragma unroll
      for (int rr = 0; rr < 4; rr++) {
        float v = acc[mi][ni][rr] + bv;
        if constexpr (MODE == 1) {
          int m = mg + rr;
          if (n < 512) oq[m * 512 + n] = (_Float16)v;
          else if (n < 1024) ok[m * 512 + (n - 512)] = (_Float16)v;
          else ov[(n - 1024) * 16384 + m] = (_Float16)v;  // V^T
        } else {
          C[(long long)(mg + rr) * ldo + n] = (OutT)v;
        }
      }
    }
  }
}

// ---- gemm9 (R3/R5-proven 8-phase): deep-pipelined f16 MFMA GEMM ----
// Tile BM x BN, BK=64, 8 waves (2M x 4N), per-wave (BM/2) x (BN/4).
// LDS: [2 bufs][2 kk-halves][rows][32 halves]; each kk-half contiguous.
// Counted vmcnt(IA+IB) once per tile; vmcnt(0) only last 2 tiles. XOR-
// swizzled LDS reads with inverse swizzle on the staging source. setprio(1)
// around MFMA clusters.
// MODE 2: 1D grid, bz = id&7 (batch->XCD), bx = j & (2^LBX-1).
template <int BM, int BN, typename OutT, int MODE, int LBX>
__global__ __launch_bounds__(512, 2) void gemm9(const _Float16* __restrict__ A,
                                                const _Float16* __restrict__ B,
                                                const float* __restrict__ bias,
                                                OutT* __restrict__ C,
                                                int lda, int ldb, int ldo, int K,
                                                long long sA, long long sB, long long sC,
                                                _Float16* __restrict__ oq,
                                                _Float16* __restrict__ ok,
                                                _Float16* __restrict__ ov) {
  constexpr int MI = BM / 32;   // per-wave m-frags
  constexpr int NI = BN / 64;   // per-wave n-frags
  constexpr int NIH = NI / 2;
  constexpr int IA = BM / 128;  // gload issues / wave / A-half
  constexpr int IB = BN / 128;

  __shared__ _Float16 Ash[2][2][BM * 32];
  __shared__ _Float16 Bsh[2][2][BN * 32];

  int bx, by, bz;
  if constexpr (MODE == 1) {
    constexpr int NBX = 1536 / BN;
    constexpr int BYX = 16384 / BM / 8;
    unsigned i = blockIdx.x;
    unsigned c = i & 7, j = i >> 3;
    by = c * BYX + j / NBX;
    bx = j % NBX;
    bz = 0;
  } else {
    unsigned i = blockIdx.x;
    unsigned c = i & 7, j = i >> 3;
    bz = c;                          // batch -> XCD: operands L2-resident
    bx = j & ((1u << LBX) - 1);
    by = j >> LBX;
  }
  A += (long long)bz * sA;
  B += (long long)bz * sB;
  C += (long long)bz * sC;
  const int m0 = by * BM, n0 = bx * BN;
  const int tid = threadIdx.x;
  const int lane = tid & 63, wave = tid >> 6;
  const int l16 = lane & 15, quad = lane >> 4;
  const int wrow = (wave >> 2) * (BM / 2);
  const int wcol = (wave & 3) * (BN / 4);
  const int srow = lane >> 2;                              // staging row in issue
  const int scol = 8 * ((lane & 3) ^ ((lane >> 3) & 3));   // inverse-swizzled col
  const int rsw = (l16 >> 1) & 3;                          // read-side swizzle

  // staging source base pointers (k-invariant)
  const _Float16* aSrc[IA];
  const _Float16* bSrc[IB];
#pragma unroll
  for (int i = 0; i < IA; i++)
    aSrc[i] = A + (long long)(m0 + (wave * IA + i) * 16 + srow) * lda + scol;
#pragma unroll
  for (int i = 0; i < IB; i++)
    bSrc[i] = B + (long long)(n0 + (wave * IB + i) * 16 + srow) * ldb + scol;

  auto stA = [&](int tile, int kk) {
#pragma unroll
    for (int i = 0; i < IA; i++)
      g2l16(aSrc[i] + tile * 64 + kk * 32,
            (_Float16*)Ash[tile & 1][kk] + (wave * IA + i) * 512);
  };
  auto stB = [&](int tile, int kk) {
#pragma unroll
    for (int i = 0; i < IB; i++)
      g2l16(bSrc[i] + tile * 64 + kk * 32,
            (_Float16*)Bsh[tile & 1][kk] + (wave * IB + i) * 512);
  };

  floatx4 acc[MI][NI] = {};
  half8 af[MI], bf[NI];

  auto ldA = [&](int buf, int kk) {
#pragma unroll
    for (int mi = 0; mi < MI; mi++)
      af[mi] = *(const half8*)(Ash[buf][kk] + (wrow + mi * 16 + l16) * 32 + (quad ^ rsw) * 8);
  };
  auto ldB0 = [&](int buf, int kk) {
#pragma unroll
    for (int j = 0; j < NIH; j++)
      bf[j] = *(const half8*)(Bsh[buf][kk] + (wcol + j * 16 + l16) * 32 + (quad ^ rsw) * 8);
  };
  auto ldB1 = [&](int buf, int kk) {
#pragma unroll
    for (int j = 0; j < NIH; j++)
      bf[NIH + j] = *(const half8*)(Bsh[buf][kk] + (wcol + (NIH + j) * 16 + l16) * 32 + (quad ^ rsw) * 8);
  };
  auto mm0 = [&]() {
#pragma unroll
    for (int mi = 0; mi < MI; mi++)
#pragma unroll
      for (int j = 0; j < NIH; j++)
        acc[mi][j] = __builtin_amdgcn_mfma_f32_16x16x32_f16(af[mi], bf[j], acc[mi][j], 0, 0, 0);
  };
  auto mm1 = [&]() {
#pragma unroll
    for (int mi = 0; mi < MI; mi++)
#pragma unroll
      for (int j = 0; j < NIH; j++)
        acc[mi][NIH + j] =
            __builtin_amdgcn_mfma_f32_16x16x32_f16(af[mi], bf[NIH + j], acc[mi][NIH + j], 0, 0, 0);
  };

#define MFMA_SEG(MMX)                                 \
  __builtin_amdgcn_s_barrier();                       \
  asm volatile("s_waitcnt lgkmcnt(0)" ::: "memory");  \
  __builtin_amdgcn_sched_barrier(0);                  \
  __builtin_amdgcn_s_setprio(1);                      \
  MMX();                                              \
  __builtin_amdgcn_s_setprio(0);                      \
  __builtin_amdgcn_sched_barrier(0);                  \
  __builtin_amdgcn_s_barrier();

  const int NT = K / 64;
  // prologue: tile0 complete + tile1 kk0 halves (FIFO order matters)
  stA(0, 0); stB(0, 0); stA(0, 1); stB(0, 1); stA(1, 0); stB(1, 0);
  if constexpr (IA + IB == 4) { VMCNT(4); } else { VMCNT(3); }
  __builtin_amdgcn_s_barrier();

  for (int t = 0; t < NT; ++t) {
    const int buf = t & 1;
    const bool s1 = (t + 1 < NT), s2 = (t + 2 < NT);
    // p1 (kk0, n-lo) | stage A1[t+1] (other buf, region dead since t-1 p4)
    ldA(buf, 0); ldB0(buf, 0);
    if (s1) stA(t + 1, 1);
    MFMA_SEG(mm0);
    // p2 (kk0, n-hi) | stage B1[t+1]
    ldB1(buf, 0);
    if (s1) stB(t + 1, 1);
    MFMA_SEG(mm1);
    // p3 (kk1, n-lo) | stage A0[t+2] (this buf, region dead since p2)
    ldA(buf, 1); ldB0(buf, 1);
    if (s2) stA(t + 2, 0);
    MFMA_SEG(mm0);
    // p4 (kk1, n-hi) | stage B0[t+2]; counted vmcnt covers next tile's reads
    ldB1(buf, 1);
    if (s2) stB(t + 2, 0);
    if (t < NT - 2) {
      if constexpr (IA + IB == 4) { VMCNT(4); } else { VMCNT(3); }
    } else {
      VMCNT(0);
    }
    MFMA_SEG(mm1);
  }
#undef MFMA_SEG

  // C/D layout (m89-verified): row(m) = quad*4 + reg, col(n) = lane&15
#pragma unroll
  for (int ni = 0; ni < NI; ni++) {
    const int n = n0 + wcol + 16 * ni + l16;
    float bv = 0.0f;
    if constexpr (MODE == 1) bv = bias[n];
#pragma unroll
    for (int mi = 0; mi < MI; mi++) {
      const int mg = m0 + wrow + 16 * mi + quad * 4;
#pragma unroll
      for (int rr = 0; rr < 4; rr++) {
        float v = acc[mi][ni][rr] + bv;
        if constexpr (MODE == 1) {
          int m = mg + rr;
          if (n < 512) oq[m * 512 + n] = (_Float16)v;
          else if (n < 1024) ok[m * 512 + (n - 512)] = (_Float16)v;
          else ov[(n - 1024) * 16384 + m] = (_Float16)v;  // V^T
        } else {
          C[(long long)(mg + rr) * ldo + n] = (OutT)v;
        }
      }
    }
  }
}

// ---- softmax over f16 rows of S (2048 wide), fp32 math, f16 in place ----
__global__ __launch_bounds__(256) void softmax_kernel(_Float16* __restrict__ S) {
  const int lane = threadIdx.x & 63;
  const int wave = threadIdx.x >> 6;
  const long long row = (long long)blockIdx.x * 4 + wave;
  _Float16* srow = S + row * 2048;
  float v[32];
  float mx = -3.4e38f;
#pragma unroll
  for (int pass = 0; pass < 4; pass++) {
    half8 f = *(const half8*)(srow + (pass * 64 + lane) * 8);
#pragma unroll
    for (int j = 0; j < 8; j++) {
      float x = (float)f[j];
      v[pass * 8 + j] = x;
      mx = fmaxf(mx, x);
    }
  }
#pragma unroll
  for (int o = 32; o > 0; o >>= 1) mx = fmaxf(mx, __shfl_xor(mx, o));
  float sum = 0.0f;
#pragma unroll
  for (int j = 0; j < 32; j++) {
    v[j] = __expf(v[j] - mx);
    sum += v[j];
  }
#pragma unroll
  for (int o = 32; o > 0; o >>= 1) sum += __shfl_xor(sum, o);
  const float inv = 1.0f / sum;
#pragma unroll
  for (int pass = 0; pass < 4; pass++) {
    half8 o8;
#pragma unroll
    for (int j = 0; j < 8; j++) o8[j] = (_Float16)(v[pass * 8 + j] * inv);
    *(half8*)(srow + (pass * 64 + lane) * 8) = o8;
  }
}

extern "C" void kernel_launch(void* const* d_in, const int* in_sizes, int n_in,
                              void* d_out, int out_size, void* d_ws, size_t ws_size,
                              hipStream_t stream) {
  const float* e  = (const float*)d_in[0];
  const float* Wq = (const float*)d_in[1];
  const float* bq = (const float*)d_in[2];
  const float* Wk = (const float*)d_in[3];
  const float* bk = (const float*)d_in[4];
  const float* Wv = (const float*)d_in[5];
  const float* bv = (const float*)d_in[6];
  float* out = (float*)d_out;
  char* ws = (char*)d_ws;

  const long long MiB = 1024LL * 1024LL;
  // big: S f16 [8][2048][2048] = 64 MiB at once; small: per-batch 8 MiB
  const bool big = ws_size >= (size_t)(115 * MiB);
  const long long base = big ? 64 * MiB : 16 * MiB;  // x16 needs 16 MiB at head

  _Float16* S    = (_Float16*)ws;
  _Float16* x16  = (_Float16*)ws;              // [0,16 MiB); dead before S written
  float*    pe32 = (float*)(ws + 16 * MiB);    // [16,20 MiB) f32; dead after prep
  _Float16* q16  = (_Float16*)(ws + base);
  _Float16* k16  = (_Float16*)(ws + base + 16 * MiB);
  _Float16* vt   = (_Float16*)(ws + base + 32 * MiB);
  _Float16* wcat = (_Float16*)(ws + base + 48 * MiB);   // 1.5 MiB
  float*    bcat = (float*)(ws + base + 48 * MiB + 1536 * 1024);

  pe_build<<<1024, 256, 0, stream>>>(pe32);
  prep_cvt_kernel<<<11264, 256, 0, stream>>>(e, pe32, x16, Wq, Wk, Wv, bq, bk, bv, wcat, bcat);

  // fused QKV: M=16384 N=1536 K=512; gemm6<128> 2-phase (best measured);
  // q/k plain, v transposed
  gemm6<128, _Float16, 1, 0><<<1536, 256, 0, stream>>>(
      x16, wcat, bcat, (_Float16*)nullptr, 512, 512, 0, 512, 0, 0, 0, q16, k16, vt);

  if (big) {
    // S = q k^T batched: M=N=2048 K=512 f16 out; 8-phase 256x256, grid 512
    gemm9<256, 256, _Float16, 2, 3><<<512, 512, 0, stream>>>(
        q16, k16, nullptr, S, 512, 512, 2048, 512,
        1048576LL, 1048576LL, 4194304LL, nullptr, nullptr, nullptr);
    softmax_kernel<<<4096, 256, 0, stream>>>(S);
    // out = P v: M=2048 N=512 K=2048; 8-phase 128x256, grid 256, NT=32
    gemm9<128, 256, float, 2, 1><<<256, 512, 0, stream>>>(
        S, vt, nullptr, out, 2048, 16384, 512, 2048,
        4194304LL, 2048LL, 1048576LL, nullptr, nullptr, nullptr);
  } else {
    for (int b = 0; b < 8; b++) {
      gemm6<128, _Float16, 0, 0><<<dim3(16, 16, 1), 256, 0, stream>>>(
          q16 + (long long)b * 1048576, k16 + (long long)b * 1048576, nullptr, S,
          512, 512, 2048, 512, 0, 0, 0, nullptr, nullptr, nullptr);
      softmax_kernel<<<512, 256, 0, stream>>>(S);
      gemm6<64, float, 0, 0><<<dim3(4, 32, 1), 256, 0, stream>>>(
          S, vt + (long long)b * 2048, nullptr, out + (long long)b * 1048576,
          2048, 16384, 512, 2048, 0, 0, 0, nullptr, nullptr, nullptr);
    }
  }
}

// Round 10
// 264.710 us; speedup vs baseline: 1.2915x; 1.0036x over previous
//
#include <hip/hip_runtime.h>
#include <hip/hip_fp16.h>

// MSAAttention: x = e + PE; q,k,v = Linear(x); out = softmax(q k^T) v
// B=8 S=2048 H=512, fp32 in/out. f16 MFMA GEMMs + fp32-math softmax.
//
// Round 16 = R9 (best, 265.7) + ONE bounded change: QKV moves to gemm6b,
// a BK=64 variant of the proven 2-phase schedule.
//  - Halves barrier-drain events (16->8 K-steps) at unchanged occupancy:
//    LDS 64 KB -> 2 blocks/CU, exactly the existing VGPR cap (72+64 acc),
//    so R6's BM=256 failure mode (residency collapse) is absent.
//  - 128-B LDS rows would be a 16-way bank conflict, so both-sides XOR
//    swizzle (8 slots: read (kk*4+quad)^(l16&7), staging source col
//    ((lane&7)^((lane>>3)&7))*8) -> 2 lanes/bank-quad per 16-lane phase =
//    free (m136). gemm9's R3 counters (conflicts 0) validate the pattern.
// Everything else byte-identical to R9: PE f32 table, prep, S = gemm9
// 256x256 (512 blocks), softmax, PV = gemm9 128x256 (256 blocks).

using half8   = __attribute__((ext_vector_type(8))) _Float16;
using half4v  = __attribute__((ext_vector_type(4))) _Float16;
using floatx4 = __attribute__((ext_vector_type(4))) float;

#define BK 32  // halves per K chunk -> 64 B LDS rows (gemm6 fallback)

#define VMCNT(N) asm volatile("s_waitcnt vmcnt(" #N ")" ::: "memory")

__device__ __forceinline__ void g2l16(const void* g, void* l) {
  // async global->LDS DMA, 16 B/lane; LDS dest = wave-uniform base + lane*16
  __builtin_amdgcn_global_load_lds((const __attribute__((address_space(1))) void*)g,
                                   (__attribute__((address_space(3))) void*)l, 16, 0, 0);
}

// ---- pe_build: pe[s][h] = h<256 ? sin(s*div[h]) : cos(s*div[h-256]) ----
__global__ __launch_bounds__(256) void pe_build(float* __restrict__ pe) {
  int i = blockIdx.x * 256 + threadIdx.x;  // 262144 threads, 4 elems each
  int idx = i * 4;
  int h = idx & 511;
  int s = idx >> 9;
  const float ks = -9.210340371976184f / 256.0f;  // -ln(10000)/256
  float4 o;
  float r[4];
#pragma unroll
  for (int j = 0; j < 4; j++) {
    int hh = h + j;
    int ii = (hh < 256) ? hh : (hh - 256);
    float ang = (float)s * __expf((float)ii * ks);
    r[j] = (hh < 256) ? __sinf(ang) : __cosf(ang);
  }
  o.x = r[0]; o.y = r[1]; o.z = r[2]; o.w = r[3];
  *(float4*)(pe + idx) = o;
}

// ---- prep (blocks 0..8191): x16 = f16(embeds + PE[table, f32])
// ---- cvt  (blocks 8192..11263): wcat f16 [1536][512] + bcat fp32 [1536]
__global__ __launch_bounds__(256) void prep_cvt_kernel(const float* __restrict__ e,
                                                       const float* __restrict__ pe,
                                                       _Float16* __restrict__ x16,
                                                       const float* __restrict__ wq,
                                                       const float* __restrict__ wk,
                                                       const float* __restrict__ wv,
                                                       const float* __restrict__ bq,
                                                       const float* __restrict__ bk,
                                                       const float* __restrict__ bv,
                                                       _Float16* __restrict__ wcat,
                                                       float* __restrict__ bcat) {
  if (blockIdx.x < 8192) {
    int t = blockIdx.x * 256 + threadIdx.x;  // 2M threads, 4 elems each
    int idx = t * 4;
    float4 ev = *(const float4*)(e + idx);
    float4 pv = *(const float4*)(pe + (idx & 1048575));  // idx mod 2048*512
    half4v o = {(_Float16)(ev.x + pv.x), (_Float16)(ev.y + pv.y),
                (_Float16)(ev.z + pv.z), (_Float16)(ev.w + pv.w)};
    *(half4v*)(x16 + idx) = o;
  } else {
    int i = (blockIdx.x - 8192) * 256 + threadIdx.x;  // 786432
    int m = i & 262143;
    const float* s = (i < 262144) ? wq : (i < 524288) ? wk : wv;
    wcat[i] = (_Float16)s[m];
    if (i < 512) bcat[i] = bq[i];
    else if (i < 1024) bcat[i] = bk[i - 512];
    else if (i < 1536) bcat[i] = bv[i - 1024];
  }
}

// ---- gemm6b: 2-phase BK=64 swizzled — QKV (MODE 1) only ----
// Tile 128x128, 4 waves (2x2), wave tile 64x64, K-step 64 (8 steps, 8
// barrier pairs vs 16 at BK=32). LDS rows 128 B = 8 x 16B slots; LDS slot s
// of row r holds global slot s^(r&7); fragment read slot (kk*4+quad)^(l16&7)
// -> 2-way bank aliasing (free). Staging: 8 rows per g2l16 issue.
__global__ __launch_bounds__(256) void gemm6b(const _Float16* __restrict__ A,
                                              const _Float16* __restrict__ B,
                                              const float* __restrict__ bias,
                                              _Float16* __restrict__ oq,
                                              _Float16* __restrict__ ok,
                                              _Float16* __restrict__ ov) {
  __shared__ _Float16 Ash[2][128 * 64];
  __shared__ _Float16 Bsh[2][128 * 64];
  // MODE1 decode: 1536 blocks = 8 XCD x 16 by x 12 bx
  unsigned i = blockIdx.x;
  unsigned c = i & 7, j = i >> 3;       // j in [0,192)
  const int by = c * 16 + j / 12;       // XCD c owns by-range [16c,16c+16)
  const int bx = j % 12;
  const int m0 = by * 128, n0 = bx * 128;
  const int tid = threadIdx.x;
  const int lane = tid & 63, wave = tid >> 6;
  const int wm = (wave >> 1) * 64, wn = (wave & 1) * 64;
  const int quad = lane >> 4, l16 = lane & 15;
  const int lrow = lane >> 3;                            // staging row in 8-row issue
  const int scol = 8 * ((lane & 7) ^ ((lane >> 3) & 7)); // inv-swizzled col (halves)
  const int rs = l16 & 7;                                // read-side row swizzle

  floatx4 acc[4][4] = {};

  auto issue = [&](int buf, int k0) {
#pragma unroll
    for (int t = 0; t < 4; t++) {                       // A: 16 issues / 4 waves
      int is = wave * 4 + t;
      g2l16(A + (long long)(m0 + is * 8 + lrow) * 512 + k0 + scol, &Ash[buf][is * 8 * 64]);
    }
#pragma unroll
    for (int t = 0; t < 4; t++) {                       // B: 16 issues / 4 waves
      int is = wave * 4 + t;
      g2l16(B + (long long)(n0 + is * 8 + lrow) * 512 + k0 + scol, &Bsh[buf][is * 8 * 64]);
    }
  };

  auto compute = [&](int buf) {
#pragma unroll
    for (int kk = 0; kk < 2; kk++) {
      half8 af[4], bf[4];
#pragma unroll
      for (int mi = 0; mi < 4; mi++)
        af[mi] = *(const half8*)&Ash[buf][(wm + 16 * mi + l16) * 64 + (((kk * 4 + quad) ^ rs) * 8)];
#pragma unroll
      for (int ni = 0; ni < 4; ni++)
        bf[ni] = *(const half8*)&Bsh[buf][(wn + 16 * ni + l16) * 64 + (((kk * 4 + quad) ^ rs) * 8)];
#pragma unroll
      for (int mi = 0; mi < 4; mi++)
#pragma unroll
        for (int ni = 0; ni < 4; ni++)
          acc[mi][ni] = __builtin_amdgcn_mfma_f32_16x16x32_f16(af[mi], bf[ni], acc[mi][ni], 0, 0, 0);
    }
  };

  issue(0, 0);
  for (int k0 = 0; k0 < 512; k0 += 128) {
    __syncthreads();                        // drains tile-k DMA
    if (k0 + 64 < 512) issue(1, k0 + 64);   // prefetch flies during compute(0)
    compute(0);
    __syncthreads();
    if (k0 + 128 < 512) issue(0, k0 + 128);
    compute(1);
  }

  // C/D layout (m89-verified): row(m) = quad*4 + reg, col(n) = lane&15
#pragma unroll
  for (int ni = 0; ni < 4; ni++) {
    const int n = n0 + wn + 16 * ni + l16;
    const float bv = bias[n];
#pragma unroll
    for (int mi = 0; mi < 4; mi++) {
      const int mg = m0 + wm + 16 * mi + quad * 4;
#pragma unroll
      for (int rr = 0; rr < 4; rr++) {
        float v = acc[mi][ni][rr] + bv;
        int m = mg + rr;
        if (n < 512) oq[m * 512 + n] = (_Float16)v;
        else if (n < 1024) ok[m * 512 + (n - 512)] = (_Float16)v;
        else ov[(long long)(n - 1024) * 16384 + m] = (_Float16)v;  // V^T
      }
    }
  }
}

// ---- gemm6 (R0-proven 2-phase): small-ws fallback path ----
template <int BM, typename OutT, int MODE, int LBX>
__global__ __launch_bounds__(256) void gemm6(const _Float16* __restrict__ A,
                                             const _Float16* __restrict__ B,
                                             const float* __restrict__ bias,
                                             OutT* __restrict__ C,
                                             int lda, int ldb, int ldo, int K,
                                             long long sA, long long sB, long long sC,
                                             _Float16* __restrict__ oq,
                                             _Float16* __restrict__ ok,
                                             _Float16* __restrict__ ov) {
  __shared__ _Float16 Ash[2][BM * BK];
  __shared__ _Float16 Bsh[2][128 * BK];
  int bx, by, bz;
  if constexpr (MODE == 2) {
    unsigned i = blockIdx.x;
    unsigned c = i & 7, j = i >> 3;
    bz = c;
    bx = j & ((1u << LBX) - 1);
    by = j >> LBX;
  } else {
    bx = blockIdx.x; by = blockIdx.y; bz = blockIdx.z;
  }
  A += (long long)bz * sA;
  B += (long long)bz * sB;
  C += (long long)bz * sC;
  const int m0 = by * BM, n0 = bx * 128;
  const int tid = threadIdx.x;
  const int lane = tid & 63, wave = tid >> 6;
  constexpr int WM = BM / 2;
  constexpr int MI = WM / 16;
  constexpr int AIt = BM / 64;
  const int wm = (wave >> 1) * WM, wn = (wave & 1) * 64;
  const int quad = lane >> 4, l16 = lane & 15;
  const int lrow = lane >> 2;
  const int lcol = (lane & 3) * 8;

  floatx4 acc[MI][4] = {};

  auto issue = [&](int buf, int k0) {
#pragma unroll
    for (int t = 0; t < AIt; t++) {
      int is = wave * AIt + t;
      g2l16(A + (long long)(m0 + is * 16 + lrow) * lda + k0 + lcol, &Ash[buf][is * 16 * BK]);
    }
#pragma unroll
    for (int t = 0; t < 2; t++) {
      int is = wave * 2 + t;
      g2l16(B + (long long)(n0 + is * 16 + lrow) * ldb + k0 + lcol, &Bsh[buf][is * 16 * BK]);
    }
  };

  auto compute = [&](int buf) {
    half8 af[MI], bf[4];
#pragma unroll
    for (int i = 0; i < MI; i++)
      af[i] = *(const half8*)&Ash[buf][(wm + 16 * i + l16) * BK + quad * 8];
#pragma unroll
    for (int i = 0; i < 4; i++)
      bf[i] = *(const half8*)&Bsh[buf][(wn + 16 * i + l16) * BK + quad * 8];
#pragma unroll
    for (int mi = 0; mi < MI; mi++)
#pragma unroll
      for (int ni = 0; ni < 4; ni++)
        acc[mi][ni] = __builtin_amdgcn_mfma_f32_16x16x32_f16(af[mi], bf[ni], acc[mi][ni], 0, 0, 0);
  };

  issue(0, 0);
  for (int k0 = 0; k0 < K; k0 += 2 * BK) {
    __syncthreads();
    if (k0 + BK < K) issue(1, k0 + BK);
    compute(0);
    __syncthreads();
    if (k0 + 2 * BK < K) issue(0, k0 + 2 * BK);
    compute(1);
  }

#pragma unroll
  for (int ni = 0; ni < 4; ni++) {
    const int n = n0 + wn + 16 * ni + l16;
#pragma unroll
    for (int mi = 0; mi < MI; mi++) {
      const int mg = m0 + wm + 16 * mi + quad * 4;
#pragma unroll
      for (int rr = 0; rr < 4; rr++)
        C[(long long)(mg + rr) * ldo + n] = (OutT)acc[mi][ni][rr];
    }
  }
}

// ---- gemm9 (R3/R5-proven 8-phase): deep-pipelined f16 MFMA GEMM ----
// MODE 2: 1D grid, bz = id&7 (batch->XCD), bx = j & (2^LBX-1).
template <int BM, int BN, typename OutT, int MODE, int LBX>
__global__ __launch_bounds__(512, 2) void gemm9(const _Float16* __restrict__ A,
                                                const _Float16* __restrict__ B,
                                                const float* __restrict__ bias,
                                                OutT* __restrict__ C,
                                                int lda, int ldb, int ldo, int K,
                                                long long sA, long long sB, long long sC,
                                                _Float16* __restrict__ oq,
                                                _Float16* __restrict__ ok,
                                                _Float16* __restrict__ ov) {
  constexpr int MI = BM / 32;
  constexpr int NI = BN / 64;
  constexpr int NIH = NI / 2;
  constexpr int IA = BM / 128;
  constexpr int IB = BN / 128;

  __shared__ _Float16 Ash[2][2][BM * 32];
  __shared__ _Float16 Bsh[2][2][BN * 32];

  int bx, by, bz;
  {
    unsigned i = blockIdx.x;
    unsigned c = i & 7, j = i >> 3;
    bz = c;                          // batch -> XCD: operands L2-resident
    bx = j & ((1u << LBX) - 1);
    by = j >> LBX;
  }
  A += (long long)bz * sA;
  B += (long long)bz * sB;
  C += (long long)bz * sC;
  const int m0 = by * BM, n0 = bx * BN;
  const int tid = threadIdx.x;
  const int lane = tid & 63, wave = tid >> 6;
  const int l16 = lane & 15, quad = lane >> 4;
  const int wrow = (wave >> 2) * (BM / 2);
  const int wcol = (wave & 3) * (BN / 4);
  const int srow = lane >> 2;
  const int scol = 8 * ((lane & 3) ^ ((lane >> 3) & 3));
  const int rsw = (l16 >> 1) & 3;

  const _Float16* aSrc[IA];
  const _Float16* bSrc[IB];
#pragma unroll
  for (int i = 0; i < IA; i++)
    aSrc[i] = A + (long long)(m0 + (wave * IA + i) * 16 + srow) * lda + scol;
#pragma unroll
  for (int i = 0; i < IB; i++)
    bSrc[i] = B + (long long)(n0 + (wave * IB + i) * 16 + srow) * ldb + scol;

  auto stA = [&](int tile, int kk) {
#pragma unroll
    for (int i = 0; i < IA; i++)
      g2l16(aSrc[i] + tile * 64 + kk * 32,
            (_Float16*)Ash[tile & 1][kk] + (wave * IA + i) * 512);
  };
  auto stB = [&](int tile, int kk) {
#pragma unroll
    for (int i = 0; i < IB; i++)
      g2l16(bSrc[i] + tile * 64 + kk * 32,
            (_Float16*)Bsh[tile & 1][kk] + (wave * IB + i) * 512);
  };

  floatx4 acc[MI][NI] = {};
  half8 af[MI], bf[NI];

  auto ldA = [&](int buf, int kk) {
#pragma unroll
    for (int mi = 0; mi < MI; mi++)
      af[mi] = *(const half8*)(Ash[buf][kk] + (wrow + mi * 16 + l16) * 32 + (quad ^ rsw) * 8);
  };
  auto ldB0 = [&](int buf, int kk) {
#pragma unroll
    for (int j = 0; j < NIH; j++)
      bf[j] = *(const half8*)(Bsh[buf][kk] + (wcol + j * 16 + l16) * 32 + (quad ^ rsw) * 8);
  };
  auto ldB1 = [&](int buf, int kk) {
#pragma unroll
    for (int j = 0; j < NIH; j++)
      bf[NIH + j] = *(const half8*)(Bsh[buf][kk] + (wcol + (NIH + j) * 16 + l16) * 32 + (quad ^ rsw) * 8);
  };
  auto mm0 = [&]() {
#pragma unroll
    for (int mi = 0; mi < MI; mi++)
#pragma unroll
      for (int j = 0; j < NIH; j++)
        acc[mi][j] = __builtin_amdgcn_mfma_f32_16x16x32_f16(af[mi], bf[j], acc[mi][j], 0, 0, 0);
  };
  auto mm1 = [&]() {
#pragma unroll
    for (int mi = 0; mi < MI; mi++)
#pragma unroll
      for (int j = 0; j < NIH; j++)
        acc[mi][NIH + j] =
            __builtin_amdgcn_mfma_f32_16x16x32_f16(af[mi], bf[NIH + j], acc[mi][NIH + j], 0, 0, 0);
  };

#define MFMA_SEG(MMX)                                 \
  __builtin_amdgcn_s_barrier();                       \
  asm volatile("s_waitcnt lgkmcnt(0)" ::: "memory");  \
  __builtin_amdgcn_sched_barrier(0);                  \
  __builtin_amdgcn_s_setprio(1);                      \
  MMX();                                              \
  __builtin_amdgcn_s_setprio(0);                      \
  __builtin_amdgcn_sched_barrier(0);                  \
  __builtin_amdgcn_s_barrier();

  const int NT = K / 64;
  stA(0, 0); stB(0, 0); stA(0, 1); stB(0, 1); stA(1, 0); stB(1, 0);
  if constexpr (IA + IB == 4) { VMCNT(4); } else { VMCNT(3); }
  __builtin_amdgcn_s_barrier();

  for (int t = 0; t < NT; ++t) {
    const int buf = t & 1;
    const bool s1 = (t + 1 < NT), s2 = (t + 2 < NT);
    ldA(buf, 0); ldB0(buf, 0);
    if (s1) stA(t + 1, 1);
    MFMA_SEG(mm0);
    ldB1(buf, 0);
    if (s1) stB(t + 1, 1);
    MFMA_SEG(mm1);
    ldA(buf, 1); ldB0(buf, 1);
    if (s2) stA(t + 2, 0);
    MFMA_SEG(mm0);
    ldB1(buf, 1);
    if (s2) stB(t + 2, 0);
    if (t < NT - 2) {
      if constexpr (IA + IB == 4) { VMCNT(4); } else { VMCNT(3); }
    } else {
      VMCNT(0);
    }
    MFMA_SEG(mm1);
  }
#undef MFMA_SEG

  // C/D layout (m89-verified): row(m) = quad*4 + reg, col(n) = lane&15
#pragma unroll
  for (int ni = 0; ni < NI; ni++) {
    const int n = n0 + wcol + 16 * ni + l16;
#pragma unroll
    for (int mi = 0; mi < MI; mi++) {
      const int mg = m0 + wrow + 16 * mi + quad * 4;
#pragma unroll
      for (int rr = 0; rr < 4; rr++)
        C[(long long)(mg + rr) * ldo + n] = (OutT)acc[mi][ni][rr];
    }
  }
}

// ---- softmax over f16 rows of S (2048 wide), fp32 math, f16 in place ----
__global__ __launch_bounds__(256) void softmax_kernel(_Float16* __restrict__ S) {
  const int lane = threadIdx.x & 63;
  const int wave = threadIdx.x >> 6;
  const long long row = (long long)blockIdx.x * 4 + wave;
  _Float16* srow = S + row * 2048;
  float v[32];
  float mx = -3.4e38f;
#pragma unroll
  for (int pass = 0; pass < 4; pass++) {
    half8 f = *(const half8*)(srow + (pass * 64 + lane) * 8);
#pragma unroll
    for (int j = 0; j < 8; j++) {
      float x = (float)f[j];
      v[pass * 8 + j] = x;
      mx = fmaxf(mx, x);
    }
  }
#pragma unroll
  for (int o = 32; o > 0; o >>= 1) mx = fmaxf(mx, __shfl_xor(mx, o));
  float sum = 0.0f;
#pragma unroll
  for (int j = 0; j < 32; j++) {
    v[j] = __expf(v[j] - mx);
    sum += v[j];
  }
#pragma unroll
  for (int o = 32; o > 0; o >>= 1) sum += __shfl_xor(sum, o);
  const float inv = 1.0f / sum;
#pragma unroll
  for (int pass = 0; pass < 4; pass++) {
    half8 o8;
#pragma unroll
    for (int j = 0; j < 8; j++) o8[j] = (_Float16)(v[pass * 8 + j] * inv);
    *(half8*)(srow + (pass * 64 + lane) * 8) = o8;
  }
}

extern "C" void kernel_launch(void* const* d_in, const int* in_sizes, int n_in,
                              void* d_out, int out_size, void* d_ws, size_t ws_size,
                              hipStream_t stream) {
  const float* e  = (const float*)d_in[0];
  const float* Wq = (const float*)d_in[1];
  const float* bq = (const float*)d_in[2];
  const float* Wk = (const float*)d_in[3];
  const float* bk = (const float*)d_in[4];
  const float* Wv = (const float*)d_in[5];
  const float* bv = (const float*)d_in[6];
  float* out = (float*)d_out;
  char* ws = (char*)d_ws;

  const long long MiB = 1024LL * 1024LL;
  // big: S f16 [8][2048][2048] = 64 MiB at once; small: per-batch 8 MiB
  const bool big = ws_size >= (size_t)(115 * MiB);
  const long long base = big ? 64 * MiB : 16 * MiB;  // x16 needs 16 MiB at head

  _Float16* S    = (_Float16*)ws;
  _Float16* x16  = (_Float16*)ws;              // [0,16 MiB); dead before S written
  float*    pe32 = (float*)(ws + 16 * MiB);    // [16,20 MiB) f32; dead after prep
  _Float16* q16  = (_Float16*)(ws + base);
  _Float16* k16  = (_Float16*)(ws + base + 16 * MiB);
  _Float16* vt   = (_Float16*)(ws + base + 32 * MiB);
  _Float16* wcat = (_Float16*)(ws + base + 48 * MiB);   // 1.5 MiB
  float*    bcat = (float*)(ws + base + 48 * MiB + 1536 * 1024);

  pe_build<<<1024, 256, 0, stream>>>(pe32);
  prep_cvt_kernel<<<11264, 256, 0, stream>>>(e, pe32, x16, Wq, Wk, Wv, bq, bk, bv, wcat, bcat);

  // fused QKV: M=16384 N=1536 K=512; gemm6b BK=64 swizzled 2-phase;
  // q/k plain, v transposed
  gemm6b<<<1536, 256, 0, stream>>>(x16, wcat, bcat, q16, k16, vt);

  if (big) {
    // S = q k^T batched: M=N=2048 K=512 f16 out; 8-phase 256x256, grid 512
    gemm9<256, 256, _Float16, 2, 3><<<512, 512, 0, stream>>>(
        q16, k16, nullptr, S, 512, 512, 2048, 512,
        1048576LL, 1048576LL, 4194304LL, nullptr, nullptr, nullptr);
    softmax_kernel<<<4096, 256, 0, stream>>>(S);
    // out = P v: M=2048 N=512 K=2048; 8-phase 128x256, grid 256, NT=32
    gemm9<128, 256, float, 2, 1><<<256, 512, 0, stream>>>(
        S, vt, nullptr, out, 2048, 16384, 512, 2048,
        4194304LL, 2048LL, 1048576LL, nullptr, nullptr, nullptr);
  } else {
    for (int b = 0; b < 8; b++) {
      gemm6<128, _Float16, 0, 0><<<dim3(16, 16, 1), 256, 0, stream>>>(
          q16 + (long long)b * 1048576, k16 + (long long)b * 1048576, nullptr, S,
          512, 512, 2048, 512, 0, 0, 0, nullptr, nullptr, nullptr);
      softmax_kernel<<<512, 256, 0, stream>>>(S);
      gemm6<64, float, 0, 0><<<dim3(4, 32, 1), 256, 0, stream>>>(
          S, vt + (long long)b * 2048, nullptr, out + (long long)b * 1048576,
          2048, 16384, 512, 2048, 0, 0, 0, nullptr, nullptr, nullptr);
    }
  }
}